// Round 5
// baseline (1218.935 us; speedup 1.0000x reference)
//
#include <hip/hip_runtime.h>
#include <hip/hip_bf16.h>
#include <stdint.h>

#define N_NODES 100000
#define MT      782          // 128-row tiles (k3)
#define MT64    1564         // 64-row stripes (k1,k2)
#define K12B    3128         // blocks for k1/k2: 1564 stripes * 8 colgrps / 4 waves
#define MPAD    (MT*128)     // 100096
#define IN_DIM  2048
#define HID     512
#define OUTD    128
#define NG      512
#define LOG2F_  0.69314718055994531f

typedef __attribute__((ext_vector_type(4))) float f32x4;
typedef __attribute__((ext_vector_type(8))) short bf16x8;

typedef const __attribute__((address_space(1))) unsigned int gas_u32;
typedef __attribute__((address_space(3))) unsigned int las_u32;

__device__ __forceinline__ void gload_lds16(const void* g, void* lds) {
  __builtin_amdgcn_global_load_lds((gas_u32*)g, (las_u32*)lds, 16, 0, 0);
}

__device__ __forceinline__ short f2bf(float f) {   // manual RNE (prep/epilogue)
  unsigned u = __builtin_bit_cast(unsigned, f);
  u = (u + 0x7fffu + ((u >> 16) & 1u)) >> 16;
  return (short)u;
}
__device__ __forceinline__ short f2bf_hw(float f) {  // hot loop: hw cvt path
  __hip_bfloat16 h = __float2bfloat16(f);
  return __builtin_bit_cast(short, h);
}
__device__ __forceinline__ float bf2f(short s) {
  unsigned u = ((unsigned)(unsigned short)s) << 16;
  return __builtin_bit_cast(float, u);
}

__device__ __forceinline__ f32x4 mfma16(bf16x8 a, bf16x8 b, f32x4 c) {
  return __builtin_amdgcn_mfma_f32_16x16x32_bf16(a, b, c, 0, 0, 0);
}

// ---------------- prep: weights -> bf16, frag-major for k1/k2 B operands ------
// wcatF: [ng=n/16][kt=k/32][lh=(k/8)%4][l16=n%16][e=k%8] -> wave b-frag (ng,kt)
//        is one contiguous 1KB block at (ng*64+kt)*512 + lane*8 shorts.
// w2tF : same with K=512 (kt in [0,16)).
// w3t  : row-major [n][k] (k3 uses gload_lds).  gencb: row-major [g][k].
__global__ void kprep(const float* __restrict__ W1, const float* __restrict__ Wj,
                      const float* __restrict__ W2, const float* __restrict__ W3,
                      const float* __restrict__ ge,
                      short* __restrict__ wcatF, short* __restrict__ w2tF,
                      short* __restrict__ w3t, short* __restrict__ gencb) {
  const int S1 = 640 * 2048, S2 = 512 * 512, S3 = 128 * 512, S4 = 512 * 128;
  int t = blockIdx.x * 256 + threadIdx.x;
  if (t < S1) {
    int k = t / 640, n = t - k * 640;
    float v = (n < 512) ? W1[(size_t)k * 512 + n] : Wj[(size_t)k * 128 + (n - 512)];
    int idx = ((((n >> 4) * 64 + (k >> 5)) * 4 + ((k >> 3) & 3)) * 16 + (n & 15)) * 8 + (k & 7);
    wcatF[idx] = f2bf(v);
  } else {
    t -= S1;
    if (t < S2) {
      int k = t >> 9, n = t & 511;
      int idx = ((((n >> 4) * 16 + (k >> 5)) * 4 + ((k >> 3) & 3)) * 16 + (n & 15)) * 8 + (k & 7);
      w2tF[idx] = f2bf(W2[(size_t)k * 512 + n]);
    } else {
      t -= S2;
      if (t < S3) {
        int n = t >> 9, k = t & 511;
        w3t[t] = f2bf(W3[(size_t)k * 128 + n]);
      } else {
        t -= S3;
        if (t < S4) gencb[t] = f2bf(ge[t]);
      }
    }
  }
}

// ---- K1: barrier-free, LDS-free. Each wave owns 64 rows x 80 cols of the
// 100096 x 640 GEMM  feat(f32) @ [W1|Wj]^T.  A read straight from feat
// (lanes of one m-frag cover whole 128B lines), B from frag-major wcatF
// (L2-resident).  No syncs -> compiler pipelines loads with counted vmcnt.
__global__ __launch_bounds__(256, 2) void k1(
    const float* __restrict__ feat, const short* __restrict__ wcatF,
    const float* __restrict__ b1, const float* __restrict__ b3,
    const float* __restrict__ bj,
    short* __restrict__ h1, short* __restrict__ jmp) {
  const int tid = threadIdx.x;
  const int lane = tid & 63;
  const int wid = blockIdx.x * 4 + (tid >> 6);
  const int l16 = lane & 15, lh = lane >> 4;
  const int stripe = wid >> 3, cg = wid & 7;
  const int m0 = stripe * 64;

  f32x4 acc[4][5];
#pragma unroll
  for (int m = 0; m < 4; m++)
#pragma unroll
    for (int n = 0; n < 5; n++) acc[m][n] = (f32x4){0.f, 0.f, 0.f, 0.f};

  const float* ap[4];
#pragma unroll
  for (int m = 0; m < 4; m++) {
    int row = m0 + m * 16 + l16;
    row = row < N_NODES ? row : N_NODES - 1;   // clamp: deterministic, masked by gid=-1 later
    ap[m] = feat + (size_t)row * IN_DIM + lh * 8;
  }
  const short* bp[5];
#pragma unroll
  for (int n = 0; n < 5; n++)
    bp[n] = wcatF + ((size_t)(cg * 5 + n) * 64) * 512 + lane * 8;

#pragma unroll 2
  for (int kt = 0; kt < 64; ++kt) {
    bf16x8 b[5];
#pragma unroll
    for (int n = 0; n < 5; n++) b[n] = *(const bf16x8*)(bp[n] + kt * 512);
    bf16x8 a[4];
#pragma unroll
    for (int m = 0; m < 4; m++) {
      f32x4 lo = *(const f32x4*)(ap[m] + (size_t)kt * 32);
      f32x4 hi = *(const f32x4*)(ap[m] + (size_t)kt * 32 + 4);
#pragma unroll
      for (int q = 0; q < 4; q++) {
        a[m][q] = f2bf_hw(lo[q]);
        a[m][q + 4] = f2bf_hw(hi[q]);
      }
    }
#pragma unroll
    for (int m = 0; m < 4; m++)
#pragma unroll
      for (int n = 0; n < 5; n++) acc[m][n] = mfma16(a[m], b[n], acc[m][n]);
  }

#pragma unroll
  for (int n = 0; n < 5; n++) {
    const int c = cg * 80 + n * 16 + l16;  // frag entirely on one side of 512
    if (c < 512) {
      const float bias = b1[c];
#pragma unroll
      for (int m = 0; m < 4; m++) {
        const int row = m0 + m * 16 + lh * 4;
#pragma unroll
        for (int r = 0; r < 4; r++) {
          float v = acc[m][n][r] + bias;
          v = v > 0.f ? v : 0.f;
          h1[(size_t)(row + r) * HID + c] = f2bf(v);
        }
      }
    } else {
      const int cj = c - 512;
      const float bias = b3[cj] + bj[cj];
#pragma unroll
      for (int m = 0; m < 4; m++) {
        const int row = m0 + m * 16 + lh * 4;
#pragma unroll
        for (int r = 0; r < 4; r++)
          jmp[(size_t)(row + r) * OUTD + cj] = f2bf(acc[m][n][r] + bias);
      }
    }
  }
}

// ---- K2: same barrier-free structure. h1(bf16)[64 rows] @ W2^T, wave = 64x64.
__global__ __launch_bounds__(256, 2) void k2(
    const short* __restrict__ h1, const short* __restrict__ w2tF,
    const float* __restrict__ b2, short* __restrict__ h2) {
  const int tid = threadIdx.x;
  const int lane = tid & 63;
  const int wid = blockIdx.x * 4 + (tid >> 6);
  const int l16 = lane & 15, lh = lane >> 4;
  const int stripe = wid >> 3, cg = wid & 7;
  const int m0 = stripe * 64;

  f32x4 acc[4][4];
#pragma unroll
  for (int m = 0; m < 4; m++)
#pragma unroll
    for (int n = 0; n < 4; n++) acc[m][n] = (f32x4){0.f, 0.f, 0.f, 0.f};

  const short* ap[4];
#pragma unroll
  for (int m = 0; m < 4; m++)
    ap[m] = h1 + (size_t)(m0 + m * 16 + l16) * HID + lh * 8;  // rows < MPAD always
  const short* bp[4];
#pragma unroll
  for (int n = 0; n < 4; n++)
    bp[n] = w2tF + ((size_t)(cg * 4 + n) * 16) * 512 + lane * 8;

#pragma unroll 2
  for (int kt = 0; kt < 16; ++kt) {
    bf16x8 b[4];
#pragma unroll
    for (int n = 0; n < 4; n++) b[n] = *(const bf16x8*)(bp[n] + kt * 512);
    bf16x8 a[4];
#pragma unroll
    for (int m = 0; m < 4; m++) a[m] = *(const bf16x8*)(ap[m] + kt * 32);
#pragma unroll
    for (int m = 0; m < 4; m++)
#pragma unroll
      for (int n = 0; n < 4; n++) acc[m][n] = mfma16(a[m], b[n], acc[m][n]);
  }

#pragma unroll
  for (int n = 0; n < 4; n++) {
    const int c = cg * 64 + n * 16 + l16;
    const float bias = b2[c];
#pragma unroll
    for (int m = 0; m < 4; m++) {
      const int row = m0 + m * 16 + lh * 4;
#pragma unroll
      for (int r = 0; r < 4; r++) {
        float v = acc[m][n][r] + bias;
        v = v > 0.f ? v : 0.f;
        h2[(size_t)(row + r) * HID + c] = f2bf(v);
      }
    }
  }
}

// ---------------- K3: l_enc = h2@W3^T + jump; res = l_enc@g_enc^T; JS loss ----
__global__ __launch_bounds__(256, 2) void k3(
    const short* __restrict__ h2, const short* __restrict__ w3t,
    const short* __restrict__ jmp, const short* __restrict__ genc,
    const int* __restrict__ gid, float* __restrict__ partials) {
  __shared__ __align__(16) short As[128 * 32];
  __shared__ __align__(16) short Bs[128 * 32];
  __shared__ __align__(16) short Ll[128 * 128];  // l_enc, XOR-swizzled rows
  __shared__ int gids[128];
  __shared__ float sred[8];
  const int mt = blockIdx.x;
  const int m0 = mt * 128;
  const int tid = threadIdx.x;
  const int lane = tid & 63, wid = tid >> 6;
  const int wr = wid >> 1, wc = wid & 1;
  const int l16 = lane & 15, lh = lane >> 4;

  if (tid < 128) {
    int r = m0 + tid;
    gids[tid] = (r < N_NODES) ? gid[r] : -1;
  }

  f32x4 acc[4][4];
#pragma unroll
  for (int i = 0; i < 4; i++)
#pragma unroll
    for (int j = 0; j < 4; j++) acc[i][j] = (f32x4){0.f, 0.f, 0.f, 0.f};

  const short* ap0 = h2 + (size_t)(m0 + (tid >> 2)) * HID + (tid & 3) * 8;
  const short* ap1 = ap0 + (size_t)64 * HID;
  const short* bp0 = w3t + (size_t)(tid >> 2) * HID + (tid & 3) * 8;
  const short* bp1 = bp0 + (size_t)64 * HID;

  for (int kt = 0; kt < HID / 32; ++kt) {
    __syncthreads();
    gload_lds16(ap0 + kt * 32, &As[tid * 8]);
    gload_lds16(ap1 + kt * 32, &As[tid * 8 + 2048]);
    gload_lds16(bp0 + kt * 32, &Bs[tid * 8]);
    gload_lds16(bp1 + kt * 32, &Bs[tid * 8 + 2048]);
    __syncthreads();
    bf16x8 a[4], b[4];
#pragma unroll
    for (int i = 0; i < 4; i++)
      a[i] = *(const bf16x8*)(&As[(wr * 64 + i * 16 + l16) * 32 + lh * 8]);
#pragma unroll
    for (int j = 0; j < 4; j++)
      b[j] = *(const bf16x8*)(&Bs[(wc * 64 + j * 16 + l16) * 32 + lh * 8]);
#pragma unroll
    for (int i = 0; i < 4; i++)
#pragma unroll
      for (int j = 0; j < 4; j++) acc[i][j] = mfma16(a[i], b[j], acc[i][j]);
  }

  // epilogue: l_enc = acc + jump (jump already holds b3+bj) -> Ll (swizzled bf16)
#pragma unroll
  for (int j = 0; j < 4; j++) {
    const int col = wc * 64 + j * 16 + l16;
#pragma unroll
    for (int i = 0; i < 4; i++) {
      const int rowb = wr * 64 + i * 16 + lh * 4;
#pragma unroll
      for (int r = 0; r < 4; r++) {
        const int row = rowb + r;
        float v = acc[i][j][r] + bf2f(jmp[(size_t)(m0 + row) * OUTD + col]);
        unsigned byte = (unsigned)row * 256u +
                        (((unsigned)col * 2u) ^ (((unsigned)(row & 7)) << 4));
        *(short*)((char*)Ll + byte) = f2bf(v);
      }
    }
  }
  __syncthreads();

  int myg[4][4];
#pragma unroll
  for (int i = 0; i < 4; i++)
#pragma unroll
    for (int r = 0; r < 4; r++) myg[i][r] = gids[wr * 64 + i * 16 + lh * 4 + r];

  float pacc = 0.f, nacc = 0.f;
  for (int nc = 0; nc < 4; ++nc) {
    f32x4 a2[4][4];
#pragma unroll
    for (int i = 0; i < 4; i++)
#pragma unroll
      for (int j = 0; j < 4; j++) a2[i][j] = (f32x4){0.f, 0.f, 0.f, 0.f};
#pragma unroll
    for (int ks = 0; ks < 4; ++ks) {
      bf16x8 af[4], bg[4];
#pragma unroll
      for (int i = 0; i < 4; i++) {
        const int row = wr * 64 + i * 16 + l16;
        unsigned byte = (unsigned)row * 256u +
                        (((unsigned)(ks * 64 + lh * 16)) ^ (((unsigned)(row & 7)) << 4));
        af[i] = *(const bf16x8*)((const char*)Ll + byte);
      }
#pragma unroll
      for (int j = 0; j < 4; j++) {
        const int g = nc * 128 + wc * 64 + j * 16 + l16;
        bg[j] = *(const bf16x8*)(genc + (size_t)g * OUTD + ks * 32 + lh * 8);
      }
#pragma unroll
      for (int i = 0; i < 4; i++)
#pragma unroll
        for (int j = 0; j < 4; j++) a2[i][j] = mfma16(af[i], bg[j], a2[i][j]);
    }
#pragma unroll
    for (int j = 0; j < 4; j++) {
      const int g = nc * 128 + wc * 64 + j * 16 + l16;
#pragma unroll
      for (int i = 0; i < 4; i++) {
#pragma unroll
        for (int r = 0; r < 4; r++) {
          float rv = a2[i][j][r];
          int gr = myg[i][r];
          float t = __expf(-fabsf(rv));
          float lg = __logf(1.f + t);
          if (gr == g)
            pacc += LOG2F_ - (fmaxf(-rv, 0.f) + lg);
          else if (gr >= 0)
            nacc += (fmaxf(rv, 0.f) + lg) - LOG2F_;
        }
      }
    }
  }

#pragma unroll
  for (int o = 32; o; o >>= 1) {
    pacc += __shfl_down(pacc, o);
    nacc += __shfl_down(nacc, o);
  }
  if (lane == 0) { sred[wid] = pacc; sred[4 + wid] = nacc; }
  __syncthreads();
  if (tid == 0) {
    partials[2 * mt] = sred[0] + sred[1] + sred[2] + sred[3];
    partials[2 * mt + 1] = sred[4] + sred[5] + sred[6] + sred[7];
  }
}

// ---------------- K4: deterministic final reduction ---------------------------
__global__ void k4(const float* __restrict__ partials, float* __restrict__ out) {
  const int tid = threadIdx.x;
  float p = 0.f, n = 0.f;
  for (int i = tid; i < MT; i += 256) {
    p += partials[2 * i];
    n += partials[2 * i + 1];
  }
#pragma unroll
  for (int o = 32; o; o >>= 1) {
    p += __shfl_down(p, o);
    n += __shfl_down(n, o);
  }
  __shared__ float sp[4], sn[4];
  const int wid = tid >> 6, lane = tid & 63;
  if (lane == 0) { sp[wid] = p; sn[wid] = n; }
  __syncthreads();
  if (tid == 0) {
    float P = sp[0] + sp[1] + sp[2] + sp[3];
    float Nn = sn[0] + sn[1] + sn[2] + sn[3];
    out[0] = Nn / (100000.0f * 511.0f) - P / 100000.0f;
  }
}

extern "C" void kernel_launch(void* const* d_in, const int* in_sizes, int n_in,
                              void* d_out, int out_size, void* d_ws, size_t ws_size,
                              hipStream_t stream) {
  const float* feat = (const float*)d_in[0];
  const float* genc_f = (const float*)d_in[1];
  const int* gid = (const int*)d_in[2];
  const float* W1 = (const float*)d_in[3];
  const float* b1 = (const float*)d_in[4];
  const float* W2 = (const float*)d_in[5];
  const float* b2 = (const float*)d_in[6];
  const float* W3 = (const float*)d_in[7];
  const float* b3 = (const float*)d_in[8];
  const float* Wj = (const float*)d_in[9];
  const float* bj = (const float*)d_in[10];
  float* out = (float*)d_out;

  char* ws = (char*)d_ws;
  float* partials = (float*)ws;                       // 782*2 f32
  short* wcatF = (short*)(ws + 8192);                 // [640][2048] bf16 frag-major
  short* w2tF = wcatF + (size_t)640 * 2048;           // [512][512] frag-major
  short* w3t = w2tF + (size_t)512 * 512;              // [128][512] row-major
  short* gencb = w3t + (size_t)128 * 512;             // [512][128] row-major
  short* h1 = gencb + (size_t)512 * 128;              // [MPAD][512]
  short* h2 = h1 + (size_t)MPAD * 512;                // [MPAD][512]
  short* jmp = h2 + (size_t)MPAD * 512;               // [MPAD][128]

  kprep<<<6656, 256, 0, stream>>>(W1, Wj, W2, W3, genc_f, wcatF, w2tF, w3t, gencb);
  k1<<<K12B, 256, 0, stream>>>(feat, wcatF, b1, b3, bj, h1, jmp);
  k2<<<K12B, 256, 0, stream>>>(h1, w2tF, b2, h2);
  k3<<<MT, 256, 0, stream>>>(h2, w3t, jmp, gencb, gid, partials);
  k4<<<1, 256, 0, stream>>>(partials, out);
}

// Round 6
// 1124.090 us; speedup vs baseline: 1.0844x; 1.0844x over previous
//
#include <hip/hip_runtime.h>
#include <hip/hip_bf16.h>
#include <stdint.h>

#define N_NODES 100000
#define MT      782          // 128-row tiles (k1,k2,k3)
#define MPAD    (MT*128)     // 100096
#define IN_DIM  2048
#define HID     512
#define OUTD    128
#define NG      512
#define LOG2F_  0.69314718055994531f

typedef __attribute__((ext_vector_type(4))) float f32x4;
typedef __attribute__((ext_vector_type(8))) short bf16x8;

typedef const __attribute__((address_space(1))) unsigned int gas_u32;
typedef __attribute__((address_space(3))) unsigned int las_u32;

__device__ __forceinline__ void gload_lds16(const void* g, void* lds) {
  __builtin_amdgcn_global_load_lds((gas_u32*)g, (las_u32*)lds, 16, 0, 0);
}

__device__ __forceinline__ short f2bf(float f) {   // manual RNE
  unsigned u = __builtin_bit_cast(unsigned, f);
  u = (u + 0x7fffu + ((u >> 16) & 1u)) >> 16;
  return (short)u;
}
__device__ __forceinline__ short f2bf_hw(float f) {  // hot loop: hw cvt
  __hip_bfloat16 h = __float2bfloat16(f);
  return __builtin_bit_cast(short, h);
}
__device__ __forceinline__ float bf2f(short s) {
  unsigned u = ((unsigned)(unsigned short)s) << 16;
  return __builtin_bit_cast(float, u);
}

__device__ __forceinline__ f32x4 mfma16(bf16x8 a, bf16x8 b, f32x4 c) {
  return __builtin_amdgcn_mfma_f32_16x16x32_bf16(a, b, c, 0, 0, 0);
}

// ---------------- prep: transpose+cast weights to bf16 B^T (row-major) -------
__global__ void kprep(const float* __restrict__ W1, const float* __restrict__ Wj,
                      const float* __restrict__ W2, const float* __restrict__ W3,
                      const float* __restrict__ ge,
                      short* __restrict__ wcat, short* __restrict__ w2t,
                      short* __restrict__ w3t, short* __restrict__ gencb) {
  const int S1 = 640 * 2048, S2 = 512 * 512, S3 = 128 * 512, S4 = 512 * 128;
  int t = blockIdx.x * 256 + threadIdx.x;
  if (t < S1) {
    int n = t >> 11, k = t & 2047;
    float v = (n < 512) ? W1[(size_t)k * 512 + n] : Wj[(size_t)k * 128 + (n - 512)];
    wcat[t] = f2bf(v);
  } else {
    t -= S1;
    if (t < S2) {
      int n = t >> 9, k = t & 511;
      w2t[t] = f2bf(W2[(size_t)k * 512 + n]);
    } else {
      t -= S2;
      if (t < S3) {
        int n = t >> 9, k = t & 511;
        w3t[t] = f2bf(W3[(size_t)k * 128 + n]);
      } else {
        t -= S3;
        if (t < S4) gencb[t] = f2bf(ge[t]);
      }
    }
  }
}

// ---- K1: feat(f32)[128 rows] @ [W1|Wj]^T(640) -> h1 (relu+b1), jump (+b3+bj)
// T3-minimum 2-phase: stage(t+1) issued BEFORE compute(t); one __syncthreads
// per step (vmcnt drain lands after compute covered the latency).
// LDS k-slot-major: A f32 [ks=k/4][row][4f32] (16B units), B bf16
// [ks2=k/8][n][8bf16] -> all frag reads lane-contiguous (conflict-free).
// 1024 thr = 16 waves (2Mw x 8Nw), wave tile 64x80, acc 4x5 f32x4.
__global__ __launch_bounds__(1024) void k1(
    const float* __restrict__ feat, const short* __restrict__ wcat,
    const float* __restrict__ b1, const float* __restrict__ b3,
    const float* __restrict__ bj,
    short* __restrict__ h1, short* __restrict__ jmp) {
  __shared__ __align__(16) char L[114688];  // A:2x16KB @0, B:2x40KB @32768
  const int tid = threadIdx.x;
  const int lane = tid & 63, w = tid >> 6;
  const int l16 = lane & 15, lh = lane >> 4;
  const int mw = w >> 3, nw = w & 7;
  const int m0 = blockIdx.x * 128;

  f32x4 acc[4][5];
#pragma unroll
  for (int m = 0; m < 4; m++)
#pragma unroll
    for (int n = 0; n < 5; n++) acc[m][n] = (f32x4){0.f, 0.f, 0.f, 0.f};

  // A staging: unit u = tid (1024 units = 16KB f32 per step)
  const float* asrc;
  {
    int row = tid & 127, ks = tid >> 7;
    int rowg = m0 + row;
    if (rowg >= N_NODES) rowg = N_NODES - 1;  // clamp; rows>=N masked by gid=-1 in k3
    asrc = feat + (size_t)rowg * IN_DIM + ks * 4;
  }
  const int adst = tid * 16;  // bytes within A-buf

  // B staging: units u = s*1024+tid, u<2560 (40KB per step)
  const short* bsrc0; const short* bsrc1; const short* bsrc2;
  int bdst0, bdst1, bdst2;
  {
    int u0 = tid, u1 = 1024 + tid, u2 = 2048 + tid;
    int k0 = u0 / 640, n0_ = u0 - k0 * 640;
    int k1_ = u1 / 640, n1_ = u1 - k1_ * 640;
    int k2_ = u2 / 640, n2_ = u2 - k2_ * 640;
    bsrc0 = wcat + (size_t)n0_ * IN_DIM + k0 * 8;
    bsrc1 = wcat + (size_t)n1_ * IN_DIM + k1_ * 8;
    bsrc2 = wcat + (size_t)n2_ * IN_DIM + k2_ * 8;
    bdst0 = u0 * 16; bdst1 = u1 * 16; bdst2 = u2 * 16;
  }
  const bool b2ok = tid < 512;

  // prologue: stage kt=0 into buf 0
  gload_lds16(asrc, L + adst);
  gload_lds16(bsrc0, L + 32768 + bdst0);
  gload_lds16(bsrc1, L + 32768 + bdst1);
  if (b2ok) gload_lds16(bsrc2, L + 32768 + bdst2);
  asrc += 32; bsrc0 += 32; bsrc1 += 32; bsrc2 += 32;
  __syncthreads();

  const int a_lds = lh * 4096 + (mw * 64 + l16) * 16;   // + m*256, hi at +2048
  const int b_lds = lh * 10240 + (nw * 80 + l16) * 16;  // + n*256

  for (int kt = 0; kt < 64; ++kt) {
    const int cur = kt & 1, nxt = cur ^ 1;
    if (kt < 63) {  // stage next BEFORE compute (overlaps with MFMA below)
      gload_lds16(asrc, L + nxt * 16384 + adst);
      gload_lds16(bsrc0, L + 32768 + nxt * 40960 + bdst0);
      gload_lds16(bsrc1, L + 32768 + nxt * 40960 + bdst1);
      if (b2ok) gload_lds16(bsrc2, L + 32768 + nxt * 40960 + bdst2);
      asrc += 32; bsrc0 += 32; bsrc1 += 32; bsrc2 += 32;
    }
    const char* Ab = L + cur * 16384;
    const char* Bb = L + 32768 + cur * 40960;
    bf16x8 b[5];
#pragma unroll
    for (int n = 0; n < 5; n++) b[n] = *(const bf16x8*)(Bb + b_lds + n * 256);
#pragma unroll
    for (int m = 0; m < 4; m++) {
      f32x4 lo = *(const f32x4*)(Ab + a_lds + m * 256);
      f32x4 hi = *(const f32x4*)(Ab + a_lds + m * 256 + 2048);
      bf16x8 a;
#pragma unroll
      for (int q = 0; q < 4; q++) { a[q] = f2bf_hw(lo[q]); a[q + 4] = f2bf_hw(hi[q]); }
#pragma unroll
      for (int n = 0; n < 5; n++) acc[m][n] = mfma16(a, b[n], acc[m][n]);
    }
    __syncthreads();  // drains vmcnt(0): next-stage complete; LDS reads done
  }

#pragma unroll
  for (int n = 0; n < 5; n++) {
    const int c = nw * 80 + n * 16 + l16;  // frag entirely on one side of 512
    if (c < 512) {
      const float bias = b1[c];
#pragma unroll
      for (int m = 0; m < 4; m++) {
        const int row = m0 + mw * 64 + m * 16 + lh * 4;
#pragma unroll
        for (int r = 0; r < 4; r++) {
          float v = acc[m][n][r] + bias;
          v = v > 0.f ? v : 0.f;
          h1[(size_t)(row + r) * HID + c] = f2bf(v);
        }
      }
    } else {
      const int cj = c - 512;
      const float bias = b3[cj] + bj[cj];
#pragma unroll
      for (int m = 0; m < 4; m++) {
        const int row = m0 + mw * 64 + m * 16 + lh * 4;
#pragma unroll
        for (int r = 0; r < 4; r++)
          jmp[(size_t)(row + r) * OUTD + cj] = f2bf(acc[m][n][r] + bias);
      }
    }
  }
}

// ---- K2: h1(bf16)[128 rows] @ W2^T (N=512) -> h2 (relu+b2). Same skeleton.
__global__ __launch_bounds__(1024) void k2(
    const short* __restrict__ h1, const short* __restrict__ w2t,
    const float* __restrict__ b2, short* __restrict__ h2) {
  __shared__ __align__(16) char L[81920];  // A:2x8KB @0, B:2x32KB @16384
  const int tid = threadIdx.x;
  const int lane = tid & 63, w = tid >> 6;
  const int l16 = lane & 15, lh = lane >> 4;
  const int mw = w >> 3, nw = w & 7;
  const int m0 = blockIdx.x * 128;

  f32x4 acc[4][4];
#pragma unroll
  for (int m = 0; m < 4; m++)
#pragma unroll
    for (int n = 0; n < 4; n++) acc[m][n] = (f32x4){0.f, 0.f, 0.f, 0.f};

  // A: 512 units (tid<512): [ks2=tid>>7][row=tid&127]
  const short* asrc = h1 + (size_t)(m0 + (tid & 127)) * HID + (tid >> 7) * 8;
  const int adst = tid * 16;
  const bool aok = tid < 512;
  // B: 2048 units: u = s*1024+tid: ks2=u>>9, n=u&511
  const short* bsrc0 = w2t + (size_t)(tid & 511) * HID + (tid >> 9) * 8;
  const short* bsrc1 = w2t + (size_t)(tid & 511) * HID + ((1024 + tid) >> 9) * 8;
  const int bdst0 = tid * 16, bdst1 = (1024 + tid) * 16;

  gload_lds16(bsrc0, L + 16384 + bdst0);
  gload_lds16(bsrc1, L + 16384 + bdst1);
  if (aok) gload_lds16(asrc, L + adst);
  asrc += 32; bsrc0 += 32; bsrc1 += 32;
  __syncthreads();

  const int a_lds = lh * 2048 + (mw * 64 + l16) * 16;   // + m*256
  const int b_lds = lh * 8192 + (nw * 64 + l16) * 16;   // + n*256

  for (int kt = 0; kt < 16; ++kt) {
    const int cur = kt & 1, nxt = cur ^ 1;
    if (kt < 15) {
      gload_lds16(bsrc0, L + 16384 + nxt * 32768 + bdst0);
      gload_lds16(bsrc1, L + 16384 + nxt * 32768 + bdst1);
      if (aok) gload_lds16(asrc, L + nxt * 8192 + adst);
      asrc += 32; bsrc0 += 32; bsrc1 += 32;
    }
    const char* Ab = L + cur * 8192;
    const char* Bb = L + 16384 + cur * 32768;
    bf16x8 b[4];
#pragma unroll
    for (int n = 0; n < 4; n++) b[n] = *(const bf16x8*)(Bb + b_lds + n * 256);
#pragma unroll
    for (int m = 0; m < 4; m++) {
      bf16x8 a = *(const bf16x8*)(Ab + a_lds + m * 256);
#pragma unroll
      for (int n = 0; n < 4; n++) acc[m][n] = mfma16(a, b[n], acc[m][n]);
    }
    __syncthreads();
  }

#pragma unroll
  for (int n = 0; n < 4; n++) {
    const int c = nw * 64 + n * 16 + l16;
    const float bias = b2[c];
#pragma unroll
    for (int m = 0; m < 4; m++) {
      const int row = m0 + mw * 64 + m * 16 + lh * 4;
#pragma unroll
      for (int r = 0; r < 4; r++) {
        float v = acc[m][n][r] + bias;
        v = v > 0.f ? v : 0.f;
        h2[(size_t)(row + r) * HID + c] = f2bf(v);
      }
    }
  }
}

// ---------------- K3: l_enc = h2@W3^T + jump; res = l_enc@g_enc^T; JS loss ----
__global__ __launch_bounds__(256, 2) void k3(
    const short* __restrict__ h2, const short* __restrict__ w3t,
    const short* __restrict__ jmp, const short* __restrict__ genc,
    const int* __restrict__ gid, float* __restrict__ partials) {
  __shared__ __align__(16) short As[128 * 32];
  __shared__ __align__(16) short Bs[128 * 32];
  __shared__ __align__(16) short Ll[128 * 128];  // l_enc, XOR-swizzled rows
  __shared__ int gids[128];
  __shared__ float sred[8];
  const int mt = blockIdx.x;
  const int m0 = mt * 128;
  const int tid = threadIdx.x;
  const int lane = tid & 63, wid = tid >> 6;
  const int wr = wid >> 1, wc = wid & 1;
  const int l16 = lane & 15, lh = lane >> 4;

  if (tid < 128) {
    int r = m0 + tid;
    gids[tid] = (r < N_NODES) ? gid[r] : -1;
  }

  f32x4 acc[4][4];
#pragma unroll
  for (int i = 0; i < 4; i++)
#pragma unroll
    for (int j = 0; j < 4; j++) acc[i][j] = (f32x4){0.f, 0.f, 0.f, 0.f};

  const short* ap0 = h2 + (size_t)(m0 + (tid >> 2)) * HID + (tid & 3) * 8;
  const short* ap1 = ap0 + (size_t)64 * HID;
  const short* bp0 = w3t + (size_t)(tid >> 2) * HID + (tid & 3) * 8;
  const short* bp1 = bp0 + (size_t)64 * HID;

  for (int kt = 0; kt < HID / 32; ++kt) {
    __syncthreads();
    gload_lds16(ap0 + kt * 32, &As[tid * 8]);
    gload_lds16(ap1 + kt * 32, &As[tid * 8 + 2048]);
    gload_lds16(bp0 + kt * 32, &Bs[tid * 8]);
    gload_lds16(bp1 + kt * 32, &Bs[tid * 8 + 2048]);
    __syncthreads();
    bf16x8 a[4], b[4];
#pragma unroll
    for (int i = 0; i < 4; i++)
      a[i] = *(const bf16x8*)(&As[(wr * 64 + i * 16 + l16) * 32 + lh * 8]);
#pragma unroll
    for (int j = 0; j < 4; j++)
      b[j] = *(const bf16x8*)(&Bs[(wc * 64 + j * 16 + l16) * 32 + lh * 8]);
#pragma unroll
    for (int i = 0; i < 4; i++)
#pragma unroll
      for (int j = 0; j < 4; j++) acc[i][j] = mfma16(a[i], b[j], acc[i][j]);
  }

  // epilogue: l_enc = acc + jump (jump already holds b3+bj) -> Ll (swizzled)
#pragma unroll
  for (int j = 0; j < 4; j++) {
    const int col = wc * 64 + j * 16 + l16;
#pragma unroll
    for (int i = 0; i < 4; i++) {
      const int rowb = wr * 64 + i * 16 + lh * 4;
#pragma unroll
      for (int r = 0; r < 4; r++) {
        const int row = rowb + r;
        float v = acc[i][j][r] + bf2f(jmp[(size_t)(m0 + row) * OUTD + col]);
        unsigned byte = (unsigned)row * 256u +
                        (((unsigned)col * 2u) ^ (((unsigned)(row & 7)) << 4));
        *(short*)((char*)Ll + byte) = f2bf(v);
      }
    }
  }
  __syncthreads();

  int myg[4][4];
#pragma unroll
  for (int i = 0; i < 4; i++)
#pragma unroll
    for (int r = 0; r < 4; r++) myg[i][r] = gids[wr * 64 + i * 16 + lh * 4 + r];

  float pacc = 0.f, nacc = 0.f;
  for (int nc = 0; nc < 4; ++nc) {
    f32x4 a2[4][4];
#pragma unroll
    for (int i = 0; i < 4; i++)
#pragma unroll
      for (int j = 0; j < 4; j++) a2[i][j] = (f32x4){0.f, 0.f, 0.f, 0.f};
#pragma unroll
    for (int ks = 0; ks < 4; ++ks) {
      bf16x8 af[4], bg[4];
#pragma unroll
      for (int i = 0; i < 4; i++) {
        const int row = wr * 64 + i * 16 + l16;
        unsigned byte = (unsigned)row * 256u +
                        (((unsigned)(ks * 64 + lh * 16)) ^ (((unsigned)(row & 7)) << 4));
        af[i] = *(const bf16x8*)((const char*)Ll + byte);
      }
#pragma unroll
      for (int j = 0; j < 4; j++) {
        const int g = nc * 128 + wc * 64 + j * 16 + l16;
        bg[j] = *(const bf16x8*)(genc + (size_t)g * OUTD + ks * 32 + lh * 8);
      }
#pragma unroll
      for (int i = 0; i < 4; i++)
#pragma unroll
        for (int j = 0; j < 4; j++) a2[i][j] = mfma16(af[i], bg[j], a2[i][j]);
    }
#pragma unroll
    for (int j = 0; j < 4; j++) {
      const int g = nc * 128 + wc * 64 + j * 16 + l16;
#pragma unroll
      for (int i = 0; i < 4; i++) {
#pragma unroll
        for (int r = 0; r < 4; r++) {
          float rv = a2[i][j][r];
          int gr = myg[i][r];
          float t = __expf(-fabsf(rv));
          float lg = __logf(1.f + t);
          if (gr == g)
            pacc += LOG2F_ - (fmaxf(-rv, 0.f) + lg);
          else if (gr >= 0)
            nacc += (fmaxf(rv, 0.f) + lg) - LOG2F_;
        }
      }
    }
  }

#pragma unroll
  for (int o = 32; o; o >>= 1) {
    pacc += __shfl_down(pacc, o);
    nacc += __shfl_down(nacc, o);
  }
  if (lane == 0) { sred[wid] = pacc; sred[4 + wid] = nacc; }
  __syncthreads();
  if (tid == 0) {
    partials[2 * mt] = sred[0] + sred[1] + sred[2] + sred[3];
    partials[2 * mt + 1] = sred[4] + sred[5] + sred[6] + sred[7];
  }
}

// ---------------- K4: deterministic final reduction ---------------------------
__global__ void k4(const float* __restrict__ partials, float* __restrict__ out) {
  const int tid = threadIdx.x;
  float p = 0.f, n = 0.f;
  for (int i = tid; i < MT; i += 256) {
    p += partials[2 * i];
    n += partials[2 * i + 1];
  }
#pragma unroll
  for (int o = 32; o; o >>= 1) {
    p += __shfl_down(p, o);
    n += __shfl_down(n, o);
  }
  __shared__ float sp[4], sn[4];
  const int wid = tid >> 6, lane = tid & 63;
  if (lane == 0) { sp[wid] = p; sn[wid] = n; }
  __syncthreads();
  if (tid == 0) {
    float P = sp[0] + sp[1] + sp[2] + sp[3];
    float Nn = sn[0] + sn[1] + sn[2] + sn[3];
    out[0] = Nn / (100000.0f * 511.0f) - P / 100000.0f;
  }
}

extern "C" void kernel_launch(void* const* d_in, const int* in_sizes, int n_in,
                              void* d_out, int out_size, void* d_ws, size_t ws_size,
                              hipStream_t stream) {
  const float* feat = (const float*)d_in[0];
  const float* genc_f = (const float*)d_in[1];
  const int* gid = (const int*)d_in[2];
  const float* W1 = (const float*)d_in[3];
  const float* b1 = (const float*)d_in[4];
  const float* W2 = (const float*)d_in[5];
  const float* b2 = (const float*)d_in[6];
  const float* W3 = (const float*)d_in[7];
  const float* b3 = (const float*)d_in[8];
  const float* Wj = (const float*)d_in[9];
  const float* bj = (const float*)d_in[10];
  float* out = (float*)d_out;

  char* ws = (char*)d_ws;
  float* partials = (float*)ws;                       // 782*2 f32
  short* wcat = (short*)(ws + 8192);                  // [640][2048] bf16 row-major
  short* w2t = wcat + (size_t)640 * 2048;             // [512][512]
  short* w3t = w2t + (size_t)512 * 512;               // [128][512]
  short* gencb = w3t + (size_t)128 * 512;             // [512][128]
  short* h1 = gencb + (size_t)512 * 128;              // [MPAD][512]
  short* h2 = h1 + (size_t)MPAD * 512;                // [MPAD][512]
  short* jmp = h2 + (size_t)MPAD * 512;               // [MPAD][128]

  kprep<<<6656, 256, 0, stream>>>(W1, Wj, W2, W3, genc_f, wcat, w2t, w3t, gencb);
  k1<<<MT, 1024, 0, stream>>>(feat, wcat, b1, b3, bj, h1, jmp);
  k2<<<MT, 1024, 0, stream>>>(h1, w2t, b2, h2);
  k3<<<MT, 256, 0, stream>>>(h2, w3t, jmp, gencb, gid, partials);
  k4<<<1, 256, 0, stream>>>(partials, out);
}

// Round 7
// 1110.624 us; speedup vs baseline: 1.0975x; 1.0121x over previous
//
#include <hip/hip_runtime.h>
#include <hip/hip_bf16.h>
#include <stdint.h>

#define N_NODES 100000
#define MT      782          // 128-row stripes
#define MPAD    (MT*128)     // 100096
#define IN_DIM  2048
#define HID     512
#define OUTD    128
#define NG      512
#define LOG2F_  0.69314718055994531f

typedef __attribute__((ext_vector_type(4))) float f32x4;
typedef __attribute__((ext_vector_type(8))) short bf16x8;

typedef const __attribute__((address_space(1))) unsigned int gas_u32;
typedef __attribute__((address_space(3))) unsigned int las_u32;

__device__ __forceinline__ void gload_lds16(const void* g, void* lds) {
  __builtin_amdgcn_global_load_lds((gas_u32*)g, (las_u32*)lds, 16, 0, 0);
}

__device__ __forceinline__ short f2bf(float f) {   // manual RNE
  unsigned u = __builtin_bit_cast(unsigned, f);
  u = (u + 0x7fffu + ((u >> 16) & 1u)) >> 16;
  return (short)u;
}
__device__ __forceinline__ short f2bf_hw(float f) {  // hot loop: hw cvt
  __hip_bfloat16 h = __float2bfloat16(f);
  return __builtin_bit_cast(short, h);
}
__device__ __forceinline__ float bf2f(short s) {
  unsigned u = ((unsigned)(unsigned short)s) << 16;
  return __builtin_bit_cast(float, u);
}

__device__ __forceinline__ f32x4 mfma16(bf16x8 a, bf16x8 b, f32x4 c) {
  return __builtin_amdgcn_mfma_f32_16x16x32_bf16(a, b, c, 0, 0, 0);
}

// ---------------- prep: transpose+cast weights to bf16 B^T (row-major) -------
__global__ void kprep(const float* __restrict__ W1, const float* __restrict__ Wj,
                      const float* __restrict__ W2, const float* __restrict__ W3,
                      const float* __restrict__ ge,
                      short* __restrict__ wcat, short* __restrict__ w2t,
                      short* __restrict__ w3t, short* __restrict__ gencb) {
  const int S1 = 640 * 2048, S2 = 512 * 512, S3 = 128 * 512, S4 = 512 * 128;
  int t = blockIdx.x * 256 + threadIdx.x;
  if (t < S1) {
    int n = t >> 11, k = t & 2047;
    float v = (n < 512) ? W1[(size_t)k * 512 + n] : Wj[(size_t)k * 128 + (n - 512)];
    wcat[t] = f2bf(v);
  } else {
    t -= S1;
    if (t < S2) {
      int n = t >> 9, k = t & 511;
      w2t[t] = f2bf(W2[(size_t)k * 512 + n]);
    } else {
      t -= S2;
      if (t < S3) {
        int n = t >> 9, k = t & 511;
        w3t[t] = f2bf(W3[(size_t)k * 128 + n]);
      } else {
        t -= S3;
        if (t < S4) gencb[t] = f2bf(ge[t]);
      }
    }
  }
}

// ---- K1: m97-clone. 128x128 tile, 256 thr / 4 waves (2x2), BK=32, single-buf
// LDS (A f32 16KB + B bf16 8KB), 2 barriers/step, gload_lds staging.
// Grid: bid = g*40 + nt*8 + r -> stripe s = g*8+r, all 5 nt of a stripe on the
// SAME XCD (bid%8==r) so feat leaves HBM once and re-reads hit that XCD's L2.
// nt<4 -> h1 cols nt*128.. (relu+b1); nt==4 -> jump (+b3+bj).
__global__ __launch_bounds__(256, 4) void k1(
    const float* __restrict__ feat, const short* __restrict__ wcat,
    const float* __restrict__ b1, const float* __restrict__ b3,
    const float* __restrict__ bj,
    short* __restrict__ h1, short* __restrict__ jmp) {
  __shared__ __align__(16) char L[24576];  // A f32 @0 (16KB), B bf16 @16384 (8KB)
  const int tid = threadIdx.x;
  const int lane = tid & 63, wid = tid >> 6;
  const int wr = wid >> 1, wc = wid & 1;
  const int l16 = lane & 15, lh = lane >> 4;
  const int bid = blockIdx.x;
  const int g = bid / 40, wi = bid - g * 40, nt = wi >> 3, r = wi & 7;
  const int s = g * 8 + r;
  if (s >= MT) return;
  const int m0 = s * 128, n0 = nt * 128;

  f32x4 acc[4][4];
#pragma unroll
  for (int m = 0; m < 4; m++)
#pragma unroll
    for (int n = 0; n < 4; n++) acc[m][n] = (f32x4){0.f, 0.f, 0.f, 0.f};

  // A staging: 1024 16B-units: u = s4*256+tid -> ks=u>>7 (0..7), row=u&127
  // LDS byte = u*16 = (ks*128+row)*16  (k-slot-major, conflict-free: R6 PMC=0)
  const float* asrc[4];
  int adst[4];
#pragma unroll
  for (int s4 = 0; s4 < 4; s4++) {
    int u = s4 * 256 + tid;
    int row = u & 127, ks = u >> 7;
    int rowg = m0 + row;
    if (rowg >= N_NODES) rowg = N_NODES - 1;  // clamp; masked via gid=-1 in k3
    asrc[s4] = feat + (size_t)rowg * IN_DIM + ks * 4;
    adst[s4] = u * 16;
  }
  // B staging: 512 units: u = s2*256+tid -> ks2=u>>7 (0..3), n=u&127
  const short* bsrc[2];
  int bdst[2];
#pragma unroll
  for (int s2 = 0; s2 < 2; s2++) {
    int u = s2 * 256 + tid;
    int n = u & 127, ks2 = u >> 7;
    bsrc[s2] = wcat + (size_t)(n0 + n) * IN_DIM + ks2 * 8;
    bdst[s2] = 16384 + u * 16;
  }

  for (int kt = 0; kt < IN_DIM / 32; ++kt) {
    __syncthreads();  // previous compute's LDS reads done
#pragma unroll
    for (int s4 = 0; s4 < 4; s4++) gload_lds16(asrc[s4] + kt * 32, L + adst[s4]);
#pragma unroll
    for (int s2 = 0; s2 < 2; s2++) gload_lds16(bsrc[s2] + kt * 32, L + bdst[s2]);
    __syncthreads();  // staging visible (vmcnt drain; hidden by 4 blocks/CU)
    bf16x8 b[4];
#pragma unroll
    for (int n = 0; n < 4; n++)
      b[n] = *(const bf16x8*)(L + 16384 + (lh * 128 + wc * 64 + n * 16 + l16) * 16);
#pragma unroll
    for (int m = 0; m < 4; m++) {
      const int rowl = wr * 64 + m * 16 + l16;
      f32x4 lo = *(const f32x4*)(L + ((lh * 2) * 128 + rowl) * 16);
      f32x4 hi = *(const f32x4*)(L + ((lh * 2 + 1) * 128 + rowl) * 16);
      bf16x8 a;
#pragma unroll
      for (int q = 0; q < 4; q++) { a[q] = f2bf_hw(lo[q]); a[q + 4] = f2bf_hw(hi[q]); }
#pragma unroll
      for (int n = 0; n < 4; n++) acc[m][n] = mfma16(a, b[n], acc[m][n]);
    }
  }

  if (nt < 4) {
#pragma unroll
    for (int n = 0; n < 4; n++) {
      const int c = n0 + wc * 64 + n * 16 + l16;
      const float bias = b1[c];
#pragma unroll
      for (int m = 0; m < 4; m++) {
        const int row = m0 + wr * 64 + m * 16 + lh * 4;
#pragma unroll
        for (int rr = 0; rr < 4; rr++) {
          float v = acc[m][n][rr] + bias;
          v = v > 0.f ? v : 0.f;
          h1[(size_t)(row + rr) * HID + c] = f2bf(v);
        }
      }
    }
  } else {
#pragma unroll
    for (int n = 0; n < 4; n++) {
      const int cj = wc * 64 + n * 16 + l16;
      const float bias = b3[cj] + bj[cj];
#pragma unroll
      for (int m = 0; m < 4; m++) {
        const int row = m0 + wr * 64 + m * 16 + lh * 4;
#pragma unroll
        for (int rr = 0; rr < 4; rr++)
          jmp[(size_t)(row + rr) * OUTD + cj] = f2bf(acc[m][n][rr] + bias);
      }
    }
  }
}

// ---- K2: m97-clone, bf16 A. h1[128] @ W2^T -> h2 (relu+b2). 16KB LDS.
__global__ __launch_bounds__(256, 4) void k2(
    const short* __restrict__ h1, const short* __restrict__ w2t,
    const float* __restrict__ b2, short* __restrict__ h2) {
  __shared__ __align__(16) char L[16384];  // A @0 (8KB), B @8192 (8KB)
  const int tid = threadIdx.x;
  const int lane = tid & 63, wid = tid >> 6;
  const int wr = wid >> 1, wc = wid & 1;
  const int l16 = lane & 15, lh = lane >> 4;
  const int bid = blockIdx.x;
  const int g = bid / 32, wi = bid - g * 32, nt = wi >> 3, r = wi & 7;
  const int s = g * 8 + r;
  if (s >= MT) return;
  const int m0 = s * 128, n0 = nt * 128;

  f32x4 acc[4][4];
#pragma unroll
  for (int m = 0; m < 4; m++)
#pragma unroll
    for (int n = 0; n < 4; n++) acc[m][n] = (f32x4){0.f, 0.f, 0.f, 0.f};

  const short* asrc[2];
  const short* bsrc[2];
  int adst[2], bdst[2];
#pragma unroll
  for (int s2 = 0; s2 < 2; s2++) {
    int u = s2 * 256 + tid;
    int row = u & 127, ks2 = u >> 7;
    asrc[s2] = h1 + (size_t)(m0 + row) * HID + ks2 * 8;
    bsrc[s2] = w2t + (size_t)(n0 + row) * HID + ks2 * 8;
    adst[s2] = u * 16;
    bdst[s2] = 8192 + u * 16;
  }

  for (int kt = 0; kt < HID / 32; ++kt) {
    __syncthreads();
#pragma unroll
    for (int s2 = 0; s2 < 2; s2++) {
      gload_lds16(asrc[s2] + kt * 32, L + adst[s2]);
      gload_lds16(bsrc[s2] + kt * 32, L + bdst[s2]);
    }
    __syncthreads();
    bf16x8 b[4];
#pragma unroll
    for (int n = 0; n < 4; n++)
      b[n] = *(const bf16x8*)(L + 8192 + (lh * 128 + wc * 64 + n * 16 + l16) * 16);
#pragma unroll
    for (int m = 0; m < 4; m++) {
      bf16x8 a = *(const bf16x8*)(L + (lh * 128 + wr * 64 + m * 16 + l16) * 16);
#pragma unroll
      for (int n = 0; n < 4; n++) acc[m][n] = mfma16(a, b[n], acc[m][n]);
    }
  }

#pragma unroll
  for (int n = 0; n < 4; n++) {
    const int c = n0 + wc * 64 + n * 16 + l16;
    const float bias = b2[c];
#pragma unroll
    for (int m = 0; m < 4; m++) {
      const int row = m0 + wr * 64 + m * 16 + lh * 4;
#pragma unroll
      for (int rr = 0; rr < 4; rr++) {
        float v = acc[m][n][rr] + bias;
        v = v > 0.f ? v : 0.f;
        h2[(size_t)(row + rr) * HID + c] = f2bf(v);
      }
    }
  }
}

// ---------------- K3: l_enc = h2@W3^T + jump; res = l_enc@g_enc^T; JS loss ----
__global__ __launch_bounds__(256, 2) void k3(
    const short* __restrict__ h2, const short* __restrict__ w3t,
    const short* __restrict__ jmp, const short* __restrict__ genc,
    const int* __restrict__ gid, float* __restrict__ partials) {
  __shared__ __align__(16) short As[128 * 32];
  __shared__ __align__(16) short Bs[128 * 32];
  __shared__ __align__(16) short Ll[128 * 128];  // l_enc, XOR-swizzled rows
  __shared__ int gids[128];
  __shared__ float sred[8];
  const int mt = blockIdx.x;
  const int m0 = mt * 128;
  const int tid = threadIdx.x;
  const int lane = tid & 63, wid = tid >> 6;
  const int wr = wid >> 1, wc = wid & 1;
  const int l16 = lane & 15, lh = lane >> 4;

  if (tid < 128) {
    int r = m0 + tid;
    gids[tid] = (r < N_NODES) ? gid[r] : -1;
  }

  f32x4 acc[4][4];
#pragma unroll
  for (int i = 0; i < 4; i++)
#pragma unroll
    for (int j = 0; j < 4; j++) acc[i][j] = (f32x4){0.f, 0.f, 0.f, 0.f};

  const short* ap0 = h2 + (size_t)(m0 + (tid >> 2)) * HID + (tid & 3) * 8;
  const short* ap1 = ap0 + (size_t)64 * HID;
  const short* bp0 = w3t + (size_t)(tid >> 2) * HID + (tid & 3) * 8;
  const short* bp1 = bp0 + (size_t)64 * HID;

  for (int kt = 0; kt < HID / 32; ++kt) {
    __syncthreads();
    gload_lds16(ap0 + kt * 32, &As[tid * 8]);
    gload_lds16(ap1 + kt * 32, &As[tid * 8 + 2048]);
    gload_lds16(bp0 + kt * 32, &Bs[tid * 8]);
    gload_lds16(bp1 + kt * 32, &Bs[tid * 8 + 2048]);
    __syncthreads();
    bf16x8 a[4], b[4];
#pragma unroll
    for (int i = 0; i < 4; i++)
      a[i] = *(const bf16x8*)(&As[(wr * 64 + i * 16 + l16) * 32 + lh * 8]);
#pragma unroll
    for (int j = 0; j < 4; j++)
      b[j] = *(const bf16x8*)(&Bs[(wc * 64 + j * 16 + l16) * 32 + lh * 8]);
#pragma unroll
    for (int i = 0; i < 4; i++)
#pragma unroll
      for (int j = 0; j < 4; j++) acc[i][j] = mfma16(a[i], b[j], acc[i][j]);
  }

  // epilogue: l_enc = acc + jump (jump already holds b3+bj) -> Ll (swizzled)
#pragma unroll
  for (int j = 0; j < 4; j++) {
    const int col = wc * 64 + j * 16 + l16;
#pragma unroll
    for (int i = 0; i < 4; i++) {
      const int rowb = wr * 64 + i * 16 + lh * 4;
#pragma unroll
      for (int r = 0; r < 4; r++) {
        const int row = rowb + r;
        float v = acc[i][j][r] + bf2f(jmp[(size_t)(m0 + row) * OUTD + col]);
        unsigned byte = (unsigned)row * 256u +
                        (((unsigned)col * 2u) ^ (((unsigned)(row & 7)) << 4));
        *(short*)((char*)Ll + byte) = f2bf(v);
      }
    }
  }
  __syncthreads();

  int myg[4][4];
#pragma unroll
  for (int i = 0; i < 4; i++)
#pragma unroll
    for (int r = 0; r < 4; r++) myg[i][r] = gids[wr * 64 + i * 16 + lh * 4 + r];

  float pacc = 0.f, nacc = 0.f;
  for (int nc = 0; nc < 4; ++nc) {
    f32x4 a2[4][4];
#pragma unroll
    for (int i = 0; i < 4; i++)
#pragma unroll
      for (int j = 0; j < 4; j++) a2[i][j] = (f32x4){0.f, 0.f, 0.f, 0.f};
#pragma unroll
    for (int ks = 0; ks < 4; ++ks) {
      bf16x8 af[4], bg[4];
#pragma unroll
      for (int i = 0; i < 4; i++) {
        const int row = wr * 64 + i * 16 + l16;
        unsigned byte = (unsigned)row * 256u +
                        (((unsigned)(ks * 64 + lh * 16)) ^ (((unsigned)(row & 7)) << 4));
        af[i] = *(const bf16x8*)((const char*)Ll + byte);
      }
#pragma unroll
      for (int j = 0; j < 4; j++) {
        const int g = nc * 128 + wc * 64 + j * 16 + l16;
        bg[j] = *(const bf16x8*)(genc + (size_t)g * OUTD + ks * 32 + lh * 8);
      }
#pragma unroll
      for (int i = 0; i < 4; i++)
#pragma unroll
        for (int j = 0; j < 4; j++) a2[i][j] = mfma16(af[i], bg[j], a2[i][j]);
    }
#pragma unroll
    for (int j = 0; j < 4; j++) {
      const int g = nc * 128 + wc * 64 + j * 16 + l16;
#pragma unroll
      for (int i = 0; i < 4; i++) {
#pragma unroll
        for (int r = 0; r < 4; r++) {
          float rv = a2[i][j][r];
          int gr = myg[i][r];
          float t = __expf(-fabsf(rv));
          float lg = __logf(1.f + t);
          if (gr == g)
            pacc += LOG2F_ - (fmaxf(-rv, 0.f) + lg);
          else if (gr >= 0)
            nacc += (fmaxf(rv, 0.f) + lg) - LOG2F_;
        }
      }
    }
  }

#pragma unroll
  for (int o = 32; o; o >>= 1) {
    pacc += __shfl_down(pacc, o);
    nacc += __shfl_down(nacc, o);
  }
  if (lane == 0) { sred[wid] = pacc; sred[4 + wid] = nacc; }
  __syncthreads();
  if (tid == 0) {
    partials[2 * mt] = sred[0] + sred[1] + sred[2] + sred[3];
    partials[2 * mt + 1] = sred[4] + sred[5] + sred[6] + sred[7];
  }
}

// ---------------- K4: deterministic final reduction ---------------------------
__global__ void k4(const float* __restrict__ partials, float* __restrict__ out) {
  const int tid = threadIdx.x;
  float p = 0.f, n = 0.f;
  for (int i = tid; i < MT; i += 256) {
    p += partials[2 * i];
    n += partials[2 * i + 1];
  }
#pragma unroll
  for (int o = 32; o; o >>= 1) {
    p += __shfl_down(p, o);
    n += __shfl_down(n, o);
  }
  __shared__ float sp[4], sn[4];
  const int wid = tid >> 6, lane = tid & 63;
  if (lane == 0) { sp[wid] = p; sn[wid] = n; }
  __syncthreads();
  if (tid == 0) {
    float P = sp[0] + sp[1] + sp[2] + sp[3];
    float Nn = sn[0] + sn[1] + sn[2] + sn[3];
    out[0] = Nn / (100000.0f * 511.0f) - P / 100000.0f;
  }
}

extern "C" void kernel_launch(void* const* d_in, const int* in_sizes, int n_in,
                              void* d_out, int out_size, void* d_ws, size_t ws_size,
                              hipStream_t stream) {
  const float* feat = (const float*)d_in[0];
  const float* genc_f = (const float*)d_in[1];
  const int* gid = (const int*)d_in[2];
  const float* W1 = (const float*)d_in[3];
  const float* b1 = (const float*)d_in[4];
  const float* W2 = (const float*)d_in[5];
  const float* b2 = (const float*)d_in[6];
  const float* W3 = (const float*)d_in[7];
  const float* b3 = (const float*)d_in[8];
  const float* Wj = (const float*)d_in[9];
  const float* bj = (const float*)d_in[10];
  float* out = (float*)d_out;

  char* ws = (char*)d_ws;
  float* partials = (float*)ws;                       // 782*2 f32
  short* wcat = (short*)(ws + 8192);                  // [640][2048] bf16 row-major
  short* w2t = wcat + (size_t)640 * 2048;             // [512][512]
  short* w3t = w2t + (size_t)512 * 512;               // [128][512]
  short* gencb = w3t + (size_t)128 * 512;             // [512][128]
  short* h1 = gencb + (size_t)512 * 128;              // [MPAD][512]
  short* h2 = h1 + (size_t)MPAD * 512;                // [MPAD][512]
  short* jmp = h2 + (size_t)MPAD * 512;               // [MPAD][128]

  kprep<<<6656, 256, 0, stream>>>(W1, Wj, W2, W3, genc_f, wcat, w2t, w3t, gencb);
  k1<<<98 * 40, 256, 0, stream>>>(feat, wcat, b1, b3, bj, h1, jmp);
  k2<<<98 * 32, 256, 0, stream>>>(h1, w2t, b2, h2);
  k3<<<MT, 256, 0, stream>>>(h2, w3t, jmp, gencb, gid, partials);
  k4<<<1, 256, 0, stream>>>(partials, out);
}

// Round 8
// 795.791 us; speedup vs baseline: 1.5317x; 1.3956x over previous
//
#include <hip/hip_runtime.h>
#include <hip/hip_bf16.h>
#include <stdint.h>

#define N_NODES 100000
#define MT      782          // 128-row tiles (k3)
#define NS256   391          // 256-row stripes (k1,k2)
#define MPAD    (MT*128)     // 100096
#define IN_DIM  2048
#define HID     512
#define OUTD    128
#define NG      512
#define LOG2F_  0.69314718055994531f

typedef __attribute__((ext_vector_type(4))) float f32x4;
typedef __attribute__((ext_vector_type(8))) short bf16x8;

typedef const __attribute__((address_space(1))) unsigned int gas_u32;
typedef __attribute__((address_space(3))) unsigned int las_u32;

__device__ __forceinline__ void gload_lds16(const void* g, void* lds) {
  __builtin_amdgcn_global_load_lds((gas_u32*)g, (las_u32*)lds, 16, 0, 0);
}

__device__ __forceinline__ short f2bf(float f) {   // manual RNE
  unsigned u = __builtin_bit_cast(unsigned, f);
  u = (u + 0x7fffu + ((u >> 16) & 1u)) >> 16;
  return (short)u;
}
__device__ __forceinline__ short f2bf_hw(float f) {  // hot loop: hw cvt
  __hip_bfloat16 h = __float2bfloat16(f);
  return __builtin_bit_cast(short, h);
}
__device__ __forceinline__ float bf2f(short s) {
  unsigned u = ((unsigned)(unsigned short)s) << 16;
  return __builtin_bit_cast(float, u);
}

__device__ __forceinline__ f32x4 mfma16(bf16x8 a, bf16x8 b, f32x4 c) {
  return __builtin_amdgcn_mfma_f32_16x16x32_bf16(a, b, c, 0, 0, 0);
}

// ---------------- prep: transpose+cast weights to bf16 B^T (row-major) -------
__global__ void kprep(const float* __restrict__ W1, const float* __restrict__ Wj,
                      const float* __restrict__ W2, const float* __restrict__ W3,
                      const float* __restrict__ ge,
                      short* __restrict__ wcat, short* __restrict__ w2t,
                      short* __restrict__ w3t, short* __restrict__ gencb) {
  const int S1 = 640 * 2048, S2 = 512 * 512, S3 = 128 * 512, S4 = 512 * 128;
  int t = blockIdx.x * 256 + threadIdx.x;
  if (t < S1) {
    int n = t >> 11, k = t & 2047;
    float v = (n < 512) ? W1[(size_t)k * 512 + n] : Wj[(size_t)k * 128 + (n - 512)];
    wcat[t] = f2bf(v);
  } else {
    t -= S1;
    if (t < S2) {
      int n = t >> 9, k = t & 511;
      w2t[t] = f2bf(W2[(size_t)k * 512 + n]);
    } else {
      t -= S2;
      if (t < S3) {
        int n = t >> 9, k = t & 511;
        w3t[t] = f2bf(W3[(size_t)k * 128 + n]);
      } else {
        t -= S3;
        if (t < S4) gencb[t] = f2bf(ge[t]);
      }
    }
  }
}

// ---- K1: 256x320 tile, 16 waves (4Mx4N, wave=64x80), BK=32, single-buf LDS.
// A(feat,f32,HBM): reg-prefetch 1 step ahead (issued in compute phase; survives
// barriers per R2 evidence), cvt->ds_write_b128. B(wcat,L2-hot 2.6MB shared by
// ALL blocks): gload_lds. Traffic = 2x feat + 391x B = 1.8GB (vs R7's 6.1GB).
// Grid: bid=g*16+half*8+r -> stripe s=g*8+r: both halves on same XCD.
__global__ __launch_bounds__(1024) void k1(
    const float* __restrict__ feat, const short* __restrict__ wcat,
    const float* __restrict__ b1, const float* __restrict__ b3,
    const float* __restrict__ bj,
    short* __restrict__ h1, short* __restrict__ jmp) {
  __shared__ __align__(16) char L[16384 + 20480];  // A bf16 [4][256][8] @0; B [4][320][8] @16384
  const int tid = threadIdx.x;
  const int lane = tid & 63, w = tid >> 6;
  const int l16 = lane & 15, lh = lane >> 4;
  const int mw = w >> 2, nw = w & 3;
  const int bid = blockIdx.x;
  const int g = bid >> 4, rem = bid & 15, half = rem >> 3, r = rem & 7;
  const int s = g * 8 + r;
  if (s >= NS256) return;
  const int m0 = s * 256;
  const int n0 = half * 320;

  f32x4 acc[4][5];
#pragma unroll
  for (int m = 0; m < 4; m++)
#pragma unroll
    for (int n = 0; n < 5; n++) acc[m][n] = (f32x4){0.f, 0.f, 0.f, 0.f};

  // A: thread t loads f32x8 (two f32x4) of row t>>2, k-chunk (t&3)*8; coalesced
  const int arow = tid >> 2, ac = tid & 3;
  int rowg = m0 + arow;
  if (rowg >= N_NODES) rowg = N_NODES - 1;  // clamp; rows>=N masked via gid=-1 in k3
  const float* ap = feat + (size_t)rowg * IN_DIM + ac * 8;
  const int awr = (ac * 256 + arow) * 16;   // LDS byte (k-slot ks=ac, row)

  // B: 1280 16B-units: u -> ks2=u/320, n=u%320 (wave-uniform: 320=5*64)
  const int u0 = tid;
  const int ks0 = u0 / 320, nu0 = u0 - ks0 * 320;
  const short* bp0 = wcat + (size_t)(n0 + nu0) * IN_DIM + ks0 * 8;
  const int u1 = 1024 + tid;
  const int ks1 = u1 / 320, nu1 = u1 - ks1 * 320;
  const short* bp1 = wcat + (size_t)(n0 + nu1) * IN_DIM + ks1 * 8;
  const bool bok = tid < 256;

  f32x4 pa0 = *(const f32x4*)(ap);
  f32x4 pa1 = *(const f32x4*)(ap + 4);

  for (int kt = 0; kt < 64; ++kt) {
    __syncthreads();  // prev step's LDS reads done
    bf16x8 av;
#pragma unroll
    for (int q = 0; q < 4; q++) { av[q] = f2bf_hw(pa0[q]); av[q + 4] = f2bf_hw(pa1[q]); }
    *(bf16x8*)(L + awr) = av;
    gload_lds16(bp0 + kt * 32, L + 16384 + u0 * 16);
    if (bok) gload_lds16(bp1 + kt * 32, L + 16384 + u1 * 16);
    __syncthreads();  // staging visible (B L2 drain ~300cyc only)
    if (kt < 63) {    // A prefetch for kt+1, issued in compute phase
      pa0 = *(const f32x4*)(ap + (kt + 1) * 32);
      pa1 = *(const f32x4*)(ap + (kt + 1) * 32 + 4);
    }
    bf16x8 b[5], a[4];
#pragma unroll
    for (int n = 0; n < 5; n++)
      b[n] = *(const bf16x8*)(L + 16384 + (lh * 320 + nw * 80 + n * 16 + l16) * 16);
#pragma unroll
    for (int m = 0; m < 4; m++)
      a[m] = *(const bf16x8*)(L + (lh * 256 + mw * 64 + m * 16 + l16) * 16);
#pragma unroll
    for (int m = 0; m < 4; m++)
#pragma unroll
      for (int n = 0; n < 5; n++) acc[m][n] = mfma16(a[m], b[n], acc[m][n]);
  }

#pragma unroll
  for (int n = 0; n < 5; n++) {
    const int c = n0 + nw * 80 + n * 16 + l16;  // frag entirely on one side of 512
    if (c < 512) {
      const float bias = b1[c];
#pragma unroll
      for (int m = 0; m < 4; m++) {
        const int row = m0 + mw * 64 + m * 16 + lh * 4;
#pragma unroll
        for (int rr = 0; rr < 4; rr++) {
          float v = acc[m][n][rr] + bias;
          v = v > 0.f ? v : 0.f;
          h1[(size_t)(row + rr) * HID + c] = f2bf(v);
        }
      }
    } else {
      const int cj = c - 512;
      const float bias = b3[cj] + bj[cj];
#pragma unroll
      for (int m = 0; m < 4; m++) {
        const int row = m0 + mw * 64 + m * 16 + lh * 4;
#pragma unroll
        for (int rr = 0; rr < 4; rr++)
          jmp[(size_t)(row + rr) * OUTD + cj] = f2bf(acc[m][n][rr] + bias);
      }
    }
  }
}

// ---- K2: same skeleton, 256x256 tile, bf16 A. h1 @ W2^T -> h2 (relu+b2).
__global__ __launch_bounds__(1024) void k2(
    const short* __restrict__ h1, const short* __restrict__ w2t,
    const float* __restrict__ b2, short* __restrict__ h2) {
  __shared__ __align__(16) char L[16384 + 16384];  // A [4][256][8] @0; B @16384
  const int tid = threadIdx.x;
  const int lane = tid & 63, w = tid >> 6;
  const int l16 = lane & 15, lh = lane >> 4;
  const int mw = w >> 2, nw = w & 3;
  const int bid = blockIdx.x;
  const int g = bid >> 4, rem = bid & 15, half = rem >> 3, r = rem & 7;
  const int s = g * 8 + r;
  if (s >= NS256) return;
  const int m0 = s * 256;
  const int n0 = half * 256;

  f32x4 acc[4][4];
#pragma unroll
  for (int m = 0; m < 4; m++)
#pragma unroll
    for (int n = 0; n < 4; n++) acc[m][n] = (f32x4){0.f, 0.f, 0.f, 0.f};

  const int arow = tid >> 2, ac = tid & 3;
  const short* ap = h1 + (size_t)(m0 + arow) * HID + ac * 8;
  const int awr = (ac * 256 + arow) * 16;

  const short* bp = w2t + (size_t)(n0 + (tid & 255)) * HID + (tid >> 8) * 8;

  bf16x8 pa = *(const bf16x8*)(ap);

  for (int kt = 0; kt < 16; ++kt) {
    __syncthreads();
    *(bf16x8*)(L + awr) = pa;
    gload_lds16(bp + kt * 32, L + 16384 + tid * 16);
    __syncthreads();
    if (kt < 15) pa = *(const bf16x8*)(ap + (kt + 1) * 32);
    bf16x8 b[4], a[4];
#pragma unroll
    for (int n = 0; n < 4; n++)
      b[n] = *(const bf16x8*)(L + 16384 + (lh * 256 + nw * 64 + n * 16 + l16) * 16);
#pragma unroll
    for (int m = 0; m < 4; m++)
      a[m] = *(const bf16x8*)(L + (lh * 256 + mw * 64 + m * 16 + l16) * 16);
#pragma unroll
    for (int m = 0; m < 4; m++)
#pragma unroll
      for (int n = 0; n < 4; n++) acc[m][n] = mfma16(a[m], b[n], acc[m][n]);
  }

#pragma unroll
  for (int n = 0; n < 4; n++) {
    const int c = n0 + nw * 64 + n * 16 + l16;
    const float bias = b2[c];
#pragma unroll
    for (int m = 0; m < 4; m++) {
      const int row = m0 + mw * 64 + m * 16 + lh * 4;
#pragma unroll
      for (int rr = 0; rr < 4; rr++) {
        float v = acc[m][n][rr] + bias;
        v = v > 0.f ? v : 0.f;
        h2[(size_t)(row + rr) * HID + c] = f2bf(v);
      }
    }
  }
}

// ---------------- K3: l_enc = h2@W3^T + jump; res = l_enc@g_enc^T; JS loss ----
__global__ __launch_bounds__(256, 2) void k3(
    const short* __restrict__ h2, const short* __restrict__ w3t,
    const short* __restrict__ jmp, const short* __restrict__ genc,
    const int* __restrict__ gid, float* __restrict__ partials) {
  __shared__ __align__(16) short As[128 * 32];
  __shared__ __align__(16) short Bs[128 * 32];
  __shared__ __align__(16) short Ll[128 * 128];  // l_enc, XOR-swizzled rows
  __shared__ int gids[128];
  __shared__ float sred[8];
  const int mt = blockIdx.x;
  const int m0 = mt * 128;
  const int tid = threadIdx.x;
  const int lane = tid & 63, wid = tid >> 6;
  const int wr = wid >> 1, wc = wid & 1;
  const int l16 = lane & 15, lh = lane >> 4;

  if (tid < 128) {
    int r = m0 + tid;
    gids[tid] = (r < N_NODES) ? gid[r] : -1;
  }

  f32x4 acc[4][4];
#pragma unroll
  for (int i = 0; i < 4; i++)
#pragma unroll
    for (int j = 0; j < 4; j++) acc[i][j] = (f32x4){0.f, 0.f, 0.f, 0.f};

  const short* ap0 = h2 + (size_t)(m0 + (tid >> 2)) * HID + (tid & 3) * 8;
  const short* ap1 = ap0 + (size_t)64 * HID;
  const short* bp0 = w3t + (size_t)(tid >> 2) * HID + (tid & 3) * 8;
  const short* bp1 = bp0 + (size_t)64 * HID;

  for (int kt = 0; kt < HID / 32; ++kt) {
    __syncthreads();
    gload_lds16(ap0 + kt * 32, &As[tid * 8]);
    gload_lds16(ap1 + kt * 32, &As[tid * 8 + 2048]);
    gload_lds16(bp0 + kt * 32, &Bs[tid * 8]);
    gload_lds16(bp1 + kt * 32, &Bs[tid * 8 + 2048]);
    __syncthreads();
    bf16x8 a[4], b[4];
#pragma unroll
    for (int i = 0; i < 4; i++)
      a[i] = *(const bf16x8*)(&As[(wr * 64 + i * 16 + l16) * 32 + lh * 8]);
#pragma unroll
    for (int j = 0; j < 4; j++)
      b[j] = *(const bf16x8*)(&Bs[(wc * 64 + j * 16 + l16) * 32 + lh * 8]);
#pragma unroll
    for (int i = 0; i < 4; i++)
#pragma unroll
      for (int j = 0; j < 4; j++) acc[i][j] = mfma16(a[i], b[j], acc[i][j]);
  }

  // epilogue: l_enc = acc + jump (jump already holds b3+bj) -> Ll (swizzled)
#pragma unroll
  for (int j = 0; j < 4; j++) {
    const int col = wc * 64 + j * 16 + l16;
#pragma unroll
    for (int i = 0; i < 4; i++) {
      const int rowb = wr * 64 + i * 16 + lh * 4;
#pragma unroll
      for (int r = 0; r < 4; r++) {
        const int row = rowb + r;
        float v = acc[i][j][r] + bf2f(jmp[(size_t)(m0 + row) * OUTD + col]);
        unsigned byte = (unsigned)row * 256u +
                        (((unsigned)col * 2u) ^ (((unsigned)(row & 7)) << 4));
        *(short*)((char*)Ll + byte) = f2bf(v);
      }
    }
  }
  __syncthreads();

  int myg[4][4];
#pragma unroll
  for (int i = 0; i < 4; i++)
#pragma unroll
    for (int r = 0; r < 4; r++) myg[i][r] = gids[wr * 64 + i * 16 + lh * 4 + r];

  float pacc = 0.f, nacc = 0.f;
  for (int nc = 0; nc < 4; ++nc) {
    f32x4 a2[4][4];
#pragma unroll
    for (int i = 0; i < 4; i++)
#pragma unroll
      for (int j = 0; j < 4; j++) a2[i][j] = (f32x4){0.f, 0.f, 0.f, 0.f};
#pragma unroll
    for (int ks = 0; ks < 4; ++ks) {
      bf16x8 af[4], bg[4];
#pragma unroll
      for (int i = 0; i < 4; i++) {
        const int row = wr * 64 + i * 16 + l16;
        unsigned byte = (unsigned)row * 256u +
                        (((unsigned)(ks * 64 + lh * 16)) ^ (((unsigned)(row & 7)) << 4));
        af[i] = *(const bf16x8*)((const char*)Ll + byte);
      }
#pragma unroll
      for (int j = 0; j < 4; j++) {
        const int g = nc * 128 + wc * 64 + j * 16 + l16;
        bg[j] = *(const bf16x8*)(genc + (size_t)g * OUTD + ks * 32 + lh * 8);
      }
#pragma unroll
      for (int i = 0; i < 4; i++)
#pragma unroll
        for (int j = 0; j < 4; j++) a2[i][j] = mfma16(af[i], bg[j], a2[i][j]);
    }
#pragma unroll
    for (int j = 0; j < 4; j++) {
      const int g = nc * 128 + wc * 64 + j * 16 + l16;
#pragma unroll
      for (int i = 0; i < 4; i++) {
#pragma unroll
        for (int r = 0; r < 4; r++) {
          float rv = a2[i][j][r];
          int gr = myg[i][r];
          float t = __expf(-fabsf(rv));
          float lg = __logf(1.f + t);
          if (gr == g)
            pacc += LOG2F_ - (fmaxf(-rv, 0.f) + lg);
          else if (gr >= 0)
            nacc += (fmaxf(rv, 0.f) + lg) - LOG2F_;
        }
      }
    }
  }

#pragma unroll
  for (int o = 32; o; o >>= 1) {
    pacc += __shfl_down(pacc, o);
    nacc += __shfl_down(nacc, o);
  }
  if (lane == 0) { sred[wid] = pacc; sred[4 + wid] = nacc; }
  __syncthreads();
  if (tid == 0) {
    partials[2 * mt] = sred[0] + sred[1] + sred[2] + sred[3];
    partials[2 * mt + 1] = sred[4] + sred[5] + sred[6] + sred[7];
  }
}

// ---------------- K4: deterministic final reduction ---------------------------
__global__ void k4(const float* __restrict__ partials, float* __restrict__ out) {
  const int tid = threadIdx.x;
  float p = 0.f, n = 0.f;
  for (int i = tid; i < MT; i += 256) {
    p += partials[2 * i];
    n += partials[2 * i + 1];
  }
#pragma unroll
  for (int o = 32; o; o >>= 1) {
    p += __shfl_down(p, o);
    n += __shfl_down(n, o);
  }
  __shared__ float sp[4], sn[4];
  const int wid = tid >> 6, lane = tid & 63;
  if (lane == 0) { sp[wid] = p; sn[wid] = n; }
  __syncthreads();
  if (tid == 0) {
    float P = sp[0] + sp[1] + sp[2] + sp[3];
    float Nn = sn[0] + sn[1] + sn[2] + sn[3];
    out[0] = Nn / (100000.0f * 511.0f) - P / 100000.0f;
  }
}

extern "C" void kernel_launch(void* const* d_in, const int* in_sizes, int n_in,
                              void* d_out, int out_size, void* d_ws, size_t ws_size,
                              hipStream_t stream) {
  const float* feat = (const float*)d_in[0];
  const float* genc_f = (const float*)d_in[1];
  const int* gid = (const int*)d_in[2];
  const float* W1 = (const float*)d_in[3];
  const float* b1 = (const float*)d_in[4];
  const float* W2 = (const float*)d_in[5];
  const float* b2 = (const float*)d_in[6];
  const float* W3 = (const float*)d_in[7];
  const float* b3 = (const float*)d_in[8];
  const float* Wj = (const float*)d_in[9];
  const float* bj = (const float*)d_in[10];
  float* out = (float*)d_out;

  char* ws = (char*)d_ws;
  float* partials = (float*)ws;                       // 782*2 f32
  short* wcat = (short*)(ws + 8192);                  // [640][2048] bf16 row-major
  short* w2t = wcat + (size_t)640 * 2048;             // [512][512]
  short* w3t = w2t + (size_t)512 * 512;               // [128][512]
  short* gencb = w3t + (size_t)128 * 512;             // [512][128]
  short* h1 = gencb + (size_t)512 * 128;              // [MPAD][512]
  short* h2 = h1 + (size_t)MPAD * 512;                // [MPAD][512]
  short* jmp = h2 + (size_t)MPAD * 512;               // [MPAD][128]

  kprep<<<6656, 256, 0, stream>>>(W1, Wj, W2, W3, genc_f, wcat, w2t, w3t, gencb);
  k1<<<49 * 16, 1024, 0, stream>>>(feat, wcat, b1, b3, bj, h1, jmp);
  k2<<<49 * 16, 1024, 0, stream>>>(h1, w2t, b2, h2);
  k3<<<MT, 256, 0, stream>>>(h2, w3t, jmp, gencb, gid, partials);
  k4<<<1, 256, 0, stream>>>(partials, out);
}